// Round 1
// baseline (164.221 us; speedup 1.0000x reference)
//
#include <hip/hip_runtime.h>
#include <hip/hip_bf16.h>

// Problem: N=8192 rows, D=256, 3 embedding matrices, ids in [0,4096).
// loss = mean over 3 pairs of ( -sum_pos(sim)/pos_cnt + sum_neg(max(1+sim,0))/neg_cnt )
// sim = normalize(a) @ normalize(b)^T / 0.5
// pos = same id, off-diagonal; neg = ~pos (includes diagonal).

#define NN 8192
#define DD 256
#define NBINS 4096
#define BM 128
#define BN 128
#define BK 64
#define NBLK_PER_PAIR (64 * 64)
#define NPART (3 * NBLK_PER_PAIR)

typedef __attribute__((ext_vector_type(8))) short short8;
typedef __attribute__((ext_vector_type(4))) float f32x4;

__device__ __forceinline__ void gload_lds16(const void* g, void* l) {
  __builtin_amdgcn_global_load_lds(
      (const __attribute__((address_space(1))) void*)(g),
      (__attribute__((address_space(3))) void*)(l), 16, 0, 0);
}

__device__ __forceinline__ unsigned short f2bf(float f) {
  unsigned int u = __float_as_uint(f);
  unsigned int r = (u + 0x7FFFu + ((u >> 16) & 1u)) >> 16;
  return (unsigned short)r;
}

// ---- init: zero histogram ----
__global__ void init_kernel(int* hist) {
  int i = blockIdx.x * 256 + threadIdx.x;
  if (i < NBINS) hist[i] = 0;
}

// ---- histogram of ids ----
__global__ void hist_kernel(const int* __restrict__ ids, int* __restrict__ hist) {
  int i = blockIdx.x * 256 + threadIdx.x;
  if (i < NN) atomicAdd(&hist[ids[i]], 1);
}

// ---- normalize rows, scale by sqrt(2) (folds 1/T=2 into the product), cast bf16 ----
// one wave per row; 4 rows per 256-thread block; 3*8192 rows total
__global__ void normalize_kernel(const float* __restrict__ e0,
                                 const float* __restrict__ e1,
                                 const float* __restrict__ e2,
                                 unsigned short* __restrict__ zbf) {
  int t = threadIdx.x, lane = t & 63, wv = t >> 6;
  int R = blockIdx.x * 4 + wv;  // 0..24575
  int mat = R >> 13, row = R & (NN - 1);
  const float* src = (mat == 0) ? e0 : (mat == 1) ? e1 : e2;
  const float4* v = (const float4*)(src + (size_t)row * DD);
  float4 x = v[lane];
  float ss = x.x * x.x + x.y * x.y + x.z * x.z + x.w * x.w;
  #pragma unroll
  for (int off = 32; off; off >>= 1) ss += __shfl_xor(ss, off);
  float norm = sqrtf(ss);
  float sc = 1.41421356237f / fmaxf(norm, 1e-12f);
  ushort4 o;
  o.x = f2bf(x.x * sc);
  o.y = f2bf(x.y * sc);
  o.z = f2bf(x.z * sc);
  o.w = f2bf(x.w * sc);
  ((ushort4*)(zbf + (size_t)R * DD))[lane] = o;
}

// ---- fused GEMM (A@B^T) + masked reduction ----
// grid (64, 64, 3); block 256 = 4 waves in 2x2; each wave 64x64 out (4x4 frags of 16x16x32)
__global__ void gemm_loss_kernel(const unsigned short* __restrict__ zbf,
                                 const int* __restrict__ ids,
                                 double* __restrict__ pPart,
                                 double* __restrict__ nPart) {
  __shared__ unsigned short sA[BM * BK];
  __shared__ unsigned short sB[BN * BK];
  __shared__ int sRid[BM];
  __shared__ int sCid[BN];
  __shared__ float sred[8];

  int t = threadIdx.x, lane = t & 63, wv = t >> 6;
  int wy = wv >> 1, wx = wv & 1;
  int bx = blockIdx.x, by = blockIdx.y, p = blockIdx.z;
  int am = (p == 2) ? 1 : 0, bmi = (p == 0) ? 1 : 2;
  const unsigned short* zA = zbf + (size_t)am * NN * DD;
  const unsigned short* zB = zbf + (size_t)bmi * NN * DD;
  int brow = by * BM, bcol = bx * BN;

  if (t < BM) sRid[t] = ids[brow + t];
  else        sCid[t - BM] = ids[bcol + (t - BM)];

  f32x4 acc[4][4] = {};

  for (int kt = 0; kt < DD / BK; ++kt) {
    // stage A,B tiles: 1024 chunks of 16B each; 4 per thread per matrix
    #pragma unroll
    for (int i = 0; i < 4; ++i) {
      int c = i * 256 + t;              // chunk 0..1023
      int row = c >> 3;                 // 8 chunks (128B) per row of BK=64 bf16
      int cc = (c & 7) * 8;             // bf16 col within tile
      gload_lds16(zA + (size_t)(brow + row) * DD + kt * BK + cc,
                  (char*)sA + (i * 256 + wv * 64) * 16);
      gload_lds16(zB + (size_t)(bcol + row) * DD + kt * BK + cc,
                  (char*)sB + (i * 256 + wv * 64) * 16);
    }
    __syncthreads();

    const short8* sAv = (const short8*)sA;
    const short8* sBv = (const short8*)sB;
    int khi = lane >> 4, rlo = lane & 15;
    #pragma unroll
    for (int ks = 0; ks < 2; ++ks) {
      short8 aF[4], bF[4];
      #pragma unroll
      for (int m = 0; m < 4; ++m)
        aF[m] = sAv[(wy * 64 + m * 16 + rlo) * (BK / 8) + ks * 4 + khi];
      #pragma unroll
      for (int n = 0; n < 4; ++n)
        bF[n] = sBv[(wx * 64 + n * 16 + rlo) * (BK / 8) + ks * 4 + khi];
      #pragma unroll
      for (int m = 0; m < 4; ++m)
        #pragma unroll
        for (int n = 0; n < 4; ++n)
          acc[m][n] = __builtin_amdgcn_mfma_f32_16x16x32_bf16(aF[m], bF[n], acc[m][n], 0, 0, 0);
    }
    __syncthreads();
  }

  // epilogue: acc element (m,n,j): row = wy*64+m*16+(lane>>4)*4+j, col = wx*64+n*16+(lane&15)
  int khi = lane >> 4, rlo = lane & 15;
  int cid[4], rid[4][4];
  #pragma unroll
  for (int n = 0; n < 4; ++n) cid[n] = sCid[wx * 64 + n * 16 + rlo];
  #pragma unroll
  for (int m = 0; m < 4; ++m)
    #pragma unroll
    for (int j = 0; j < 4; ++j) rid[m][j] = sRid[wy * 64 + m * 16 + khi * 4 + j];

  float psum = 0.f, nsum = 0.f;
  bool diagBlk = (bx == by);
  #pragma unroll
  for (int m = 0; m < 4; ++m) {
    #pragma unroll
    for (int n = 0; n < 4; ++n) {
      #pragma unroll
      for (int j = 0; j < 4; ++j) {
        float s = acc[m][n][j];  // already sim/T thanks to sqrt(2) prescale
        bool eq = (rid[m][j] == cid[n]);
        if (diagBlk) {
          int r = wy * 64 + m * 16 + khi * 4 + j;
          int c = wx * 64 + n * 16 + rlo;
          eq = eq && (r != c);
        }
        psum += eq ? s : 0.f;
        float h = fmaxf(1.f + s, 0.f);
        nsum += eq ? 0.f : h;
      }
    }
  }

  #pragma unroll
  for (int off = 32; off; off >>= 1) {
    psum += __shfl_down(psum, off);
    nsum += __shfl_down(nsum, off);
  }
  if (lane == 0) { sred[wv * 2] = psum; sred[wv * 2 + 1] = nsum; }
  __syncthreads();
  if (t == 0) {
    float pp = sred[0] + sred[2] + sred[4] + sred[6];
    float nn2 = sred[1] + sred[3] + sred[5] + sred[7];
    int bid = (p * gridDim.y + by) * gridDim.x + bx;
    pPart[bid] = (double)pp;
    nPart[bid] = (double)nn2;
  }
}

// ---- finalize: reduce partials + counts -> scalar loss ----
__global__ void finalize_kernel(const int* __restrict__ hist,
                                const double* __restrict__ pPart,
                                const double* __restrict__ nPart,
                                float* __restrict__ out) {
  int t = threadIdx.x, lane = t & 63, wv = t >> 6;
  long long c2 = 0;
  for (int i = t; i < NBINS; i += 256) {
    long long c = hist[i];
    c2 += c * c;
  }
  double ps = 0.0, ns = 0.0;
  for (int i = t; i < NPART; i += 256) {
    ps += pPart[i];
    ns += nPart[i];
  }
  #pragma unroll
  for (int off = 32; off; off >>= 1) {
    ps += __shfl_down(ps, off);
    ns += __shfl_down(ns, off);
    c2 += __shfl_down(c2, off);
  }
  __shared__ double rp[4], rn[4];
  __shared__ long long rc[4];
  if (lane == 0) { rp[wv] = ps; rn[wv] = ns; rc[wv] = c2; }
  __syncthreads();
  if (t == 0) {
    double P = rp[0] + rp[1] + rp[2] + rp[3];
    double Nh = rn[0] + rn[1] + rn[2] + rn[3];
    long long C2 = rc[0] + rc[1] + rc[2] + rc[3];
    double pc = (double)(C2 - NN);
    double nc = (double)NN * (double)NN - pc;
    out[0] = (float)(-P / (3.0 * pc) + Nh / (3.0 * nc));
  }
}

extern "C" void kernel_launch(void* const* d_in, const int* in_sizes, int n_in,
                              void* d_out, int out_size, void* d_ws, size_t ws_size,
                              hipStream_t stream) {
  const float* e0 = (const float*)d_in[0];
  const float* e1 = (const float*)d_in[1];
  const float* e2 = (const float*)d_in[2];
  const int* ids = (const int*)d_in[3];
  float* out = (float*)d_out;

  char* ws = (char*)d_ws;
  unsigned short* zbf = (unsigned short*)ws;                    // 3*8192*256*2 = 12,582,912 B
  int* hist = (int*)(ws + 12582912);                            // 16,384 B
  double* pPart = (double*)(ws + 12582912 + 16384);             // NPART*8
  double* nPart = pPart + NPART;

  hipLaunchKernelGGL(init_kernel, dim3(16), dim3(256), 0, stream, hist);
  hipLaunchKernelGGL(hist_kernel, dim3(32), dim3(256), 0, stream, ids, hist);
  hipLaunchKernelGGL(normalize_kernel, dim3((3 * NN) / 4), dim3(256), 0, stream,
                     e0, e1, e2, zbf);
  hipLaunchKernelGGL(gemm_loss_kernel, dim3(64, 64, 3), dim3(256), 0, stream,
                     zbf, ids, pPart, nPart);
  hipLaunchKernelGGL(finalize_kernel, dim3(1), dim3(256), 0, stream,
                     hist, pPart, nPart, out);
}

// Round 2
// 156.889 us; speedup vs baseline: 1.0467x; 1.0467x over previous
//
#include <hip/hip_runtime.h>
#include <hip/hip_bf16.h>

// Problem: N=8192 rows, D=256, 3 embedding matrices, ids in [0,4096).
// loss = mean over 3 pairs of ( -sum_pos(sim)/pos_cnt + sum_neg(max(1+sim,0))/neg_cnt )
// sim = normalize(a) @ normalize(b)^T / 0.5
// pos = same id, off-diagonal; neg = ~pos (includes diagonal).
//
// R1: + LDS XOR swizzle (slot ^= row&7) both-sides (pre-swizzled global src for
//     global_load_lds, swizzled ds_read index) to kill the 16-way bank conflict;
//     + __any(eq)-guarded rare path in epilogue (~7 -> ~4 VALU/elem);
//     + hoisted staging addresses, unrolled kt loop.

#define NN 8192
#define DD 256
#define NBINS 4096
#define BM 128
#define BN 128
#define BK 64
#define NBLK_PER_PAIR (64 * 64)
#define NPART (3 * NBLK_PER_PAIR)

typedef __attribute__((ext_vector_type(8))) short short8;
typedef __attribute__((ext_vector_type(4))) float f32x4;

__device__ __forceinline__ void gload_lds16(const void* g, void* l) {
  __builtin_amdgcn_global_load_lds(
      (const __attribute__((address_space(1))) void*)(g),
      (__attribute__((address_space(3))) void*)(l), 16, 0, 0);
}

__device__ __forceinline__ unsigned short f2bf(float f) {
  unsigned int u = __float_as_uint(f);
  unsigned int r = (u + 0x7FFFu + ((u >> 16) & 1u)) >> 16;
  return (unsigned short)r;
}

// ---- init: zero histogram ----
__global__ void init_kernel(int* hist) {
  int i = blockIdx.x * 256 + threadIdx.x;
  if (i < NBINS) hist[i] = 0;
}

// ---- histogram of ids ----
__global__ void hist_kernel(const int* __restrict__ ids, int* __restrict__ hist) {
  int i = blockIdx.x * 256 + threadIdx.x;
  if (i < NN) atomicAdd(&hist[ids[i]], 1);
}

// ---- normalize rows, scale by sqrt(2) (folds 1/T=2 into the product), cast bf16 ----
__global__ void normalize_kernel(const float* __restrict__ e0,
                                 const float* __restrict__ e1,
                                 const float* __restrict__ e2,
                                 unsigned short* __restrict__ zbf) {
  int t = threadIdx.x, lane = t & 63, wv = t >> 6;
  int R = blockIdx.x * 4 + wv;  // 0..24575
  int mat = R >> 13, row = R & (NN - 1);
  const float* src = (mat == 0) ? e0 : (mat == 1) ? e1 : e2;
  const float4* v = (const float4*)(src + (size_t)row * DD);
  float4 x = v[lane];
  float ss = x.x * x.x + x.y * x.y + x.z * x.z + x.w * x.w;
  #pragma unroll
  for (int off = 32; off; off >>= 1) ss += __shfl_xor(ss, off);
  float norm = sqrtf(ss);
  float sc = 1.41421356237f / fmaxf(norm, 1e-12f);
  ushort4 o;
  o.x = f2bf(x.x * sc);
  o.y = f2bf(x.y * sc);
  o.z = f2bf(x.z * sc);
  o.w = f2bf(x.w * sc);
  ((ushort4*)(zbf + (size_t)R * DD))[lane] = o;
}

// ---- fused GEMM (A@B^T) + masked reduction ----
// grid (64, 64, 3); block 256 = 4 waves in 2x2; each wave 64x64 out (4x4 frags of 16x16x32)
__global__ void gemm_loss_kernel(const unsigned short* __restrict__ zbf,
                                 const int* __restrict__ ids,
                                 double* __restrict__ pPart,
                                 double* __restrict__ nPart) {
  __shared__ unsigned short sA[BM * BK];
  __shared__ unsigned short sB[BN * BK];
  __shared__ int sRid[BM];
  __shared__ int sCid[BN];
  __shared__ float sred[8];

  int t = threadIdx.x, lane = t & 63, wv = t >> 6;
  int wy = wv >> 1, wx = wv & 1;
  int bx = blockIdx.x, by = blockIdx.y, p = blockIdx.z;
  int am = (p == 2) ? 1 : 0, bmi = (p == 0) ? 1 : 2;
  const unsigned short* zA = zbf + (size_t)am * NN * DD;
  const unsigned short* zB = zbf + (size_t)bmi * NN * DD;
  int brow = by * BM, bcol = bx * BN;

  if (t < BM) sRid[t] = ids[brow + t];
  else        sCid[t - BM] = ids[bcol + (t - BM)];

  // hoisted staging addresses. LDS chunk q (16B) holds global slot (q&7)^(row&7)
  // of row q>>3 -> linear LDS dest, inverse-swizzled global source (rule #21).
  const unsigned short* gA[4];
  const unsigned short* gB[4];
  char* lA[4];
  char* lB[4];
  #pragma unroll
  for (int i = 0; i < 4; ++i) {
    int c = i * 256 + t;                  // LDS chunk index 0..1023 (linear)
    int row = c >> 3;
    int slot = (c & 7) ^ (row & 7);       // pre-swizzled source slot
    gA[i] = zA + (size_t)(brow + row) * DD + slot * 8;
    gB[i] = zB + (size_t)(bcol + row) * DD + slot * 8;
    lA[i] = (char*)sA + (i * 256 + wv * 64) * 16;
    lB[i] = (char*)sB + (i * 256 + wv * 64) * 16;
  }

  f32x4 acc[4][4] = {};
  int khi = lane >> 4, rlo = lane & 15;
  int swz = rlo & 7;                       // row&7 for all fragment rows this lane reads

  const short8* sAv = (const short8*)sA;
  const short8* sBv = (const short8*)sB;

  #pragma unroll
  for (int kt = 0; kt < DD / BK; ++kt) {
    #pragma unroll
    for (int i = 0; i < 4; ++i) {
      gload_lds16(gA[i] + kt * BK, lA[i]);
      gload_lds16(gB[i] + kt * BK, lB[i]);
    }
    __syncthreads();

    #pragma unroll
    for (int ks = 0; ks < 2; ++ks) {
      short8 aF[4], bF[4];
      int kc = ks * 4 + khi;
      int kcs = kc ^ swz;                  // swizzled slot for this lane
      #pragma unroll
      for (int m = 0; m < 4; ++m)
        aF[m] = sAv[(wy * 64 + m * 16 + rlo) * (BK / 8) + kcs];
      #pragma unroll
      for (int n = 0; n < 4; ++n)
        bF[n] = sBv[(wx * 64 + n * 16 + rlo) * (BK / 8) + kcs];
      #pragma unroll
      for (int m = 0; m < 4; ++m)
        #pragma unroll
        for (int n = 0; n < 4; ++n)
          acc[m][n] = __builtin_amdgcn_mfma_f32_16x16x32_bf16(aF[m], bF[n], acc[m][n], 0, 0, 0);
    }
    __syncthreads();
  }

  // epilogue: acc element (m,n,j): row = wy*64+m*16+(lane>>4)*4+j, col = wx*64+n*16+(lane&15)
  int cid[4], rid[4][4];
  #pragma unroll
  for (int n = 0; n < 4; ++n) cid[n] = sCid[wx * 64 + n * 16 + rlo];
  #pragma unroll
  for (int m = 0; m < 4; ++m)
    #pragma unroll
    for (int j = 0; j < 4; ++j) rid[m][j] = sRid[wy * 64 + m * 16 + khi * 4 + j];

  float psum = 0.f, nsum = 0.f;
  bool diagBlk = (bx == by);
  #pragma unroll
  for (int m = 0; m < 4; ++m) {
    #pragma unroll
    for (int n = 0; n < 4; ++n) {
      #pragma unroll
      for (int j = 0; j < 4; ++j) {
        float s = acc[m][n][j];  // already sim/T thanks to sqrt(2) prescale
        float h = fmaxf(1.f + s, 0.f);
        nsum += h;
        bool eq = (rid[m][j] == cid[n]);
        if (__any(eq)) {         // rare (~1.6% of element-groups)
          if (diagBlk) {
            int r = wy * 64 + m * 16 + khi * 4 + j;
            int c = wx * 64 + n * 16 + rlo;
            eq = eq && (r != c);
          }
          psum += eq ? s : 0.f;
          nsum -= eq ? h : 0.f;
        }
      }
    }
  }

  #pragma unroll
  for (int off = 32; off; off >>= 1) {
    psum += __shfl_down(psum, off);
    nsum += __shfl_down(nsum, off);
  }
  if (lane == 0) { sred[wv * 2] = psum; sred[wv * 2 + 1] = nsum; }
  __syncthreads();
  if (t == 0) {
    float pp = sred[0] + sred[2] + sred[4] + sred[6];
    float nn2 = sred[1] + sred[3] + sred[5] + sred[7];
    int bid = (p * gridDim.y + by) * gridDim.x + bx;
    pPart[bid] = (double)pp;
    nPart[bid] = (double)nn2;
  }
}

// ---- finalize: reduce partials + counts -> scalar loss ----
__global__ void finalize_kernel(const int* __restrict__ hist,
                                const double* __restrict__ pPart,
                                const double* __restrict__ nPart,
                                float* __restrict__ out) {
  int t = threadIdx.x, lane = t & 63, wv = t >> 6;
  long long c2 = 0;
  for (int i = t; i < NBINS; i += 256) {
    long long c = hist[i];
    c2 += c * c;
  }
  double ps = 0.0, ns = 0.0;
  for (int i = t; i < NPART; i += 256) {
    ps += pPart[i];
    ns += nPart[i];
  }
  #pragma unroll
  for (int off = 32; off; off >>= 1) {
    ps += __shfl_down(ps, off);
    ns += __shfl_down(ns, off);
    c2 += __shfl_down(c2, off);
  }
  __shared__ double rp[4], rn[4];
  __shared__ long long rc[4];
  if (lane == 0) { rp[wv] = ps; rn[wv] = ns; rc[wv] = c2; }
  __syncthreads();
  if (t == 0) {
    double P = rp[0] + rp[1] + rp[2] + rp[3];
    double Nh = rn[0] + rn[1] + rn[2] + rn[3];
    long long C2 = rc[0] + rc[1] + rc[2] + rc[3];
    double pc = (double)(C2 - NN);
    double nc = (double)NN * (double)NN - pc;
    out[0] = (float)(-P / (3.0 * pc) + Nh / (3.0 * nc));
  }
}

extern "C" void kernel_launch(void* const* d_in, const int* in_sizes, int n_in,
                              void* d_out, int out_size, void* d_ws, size_t ws_size,
                              hipStream_t stream) {
  const float* e0 = (const float*)d_in[0];
  const float* e1 = (const float*)d_in[1];
  const float* e2 = (const float*)d_in[2];
  const int* ids = (const int*)d_in[3];
  float* out = (float*)d_out;

  char* ws = (char*)d_ws;
  unsigned short* zbf = (unsigned short*)ws;                    // 12,582,912 B
  int* hist = (int*)(ws + 12582912);                            // 16,384 B
  double* pPart = (double*)(ws + 12582912 + 16384);             // NPART*8
  double* nPart = pPart + NPART;

  hipLaunchKernelGGL(init_kernel, dim3(16), dim3(256), 0, stream, hist);
  hipLaunchKernelGGL(hist_kernel, dim3(32), dim3(256), 0, stream, ids, hist);
  hipLaunchKernelGGL(normalize_kernel, dim3((3 * NN) / 4), dim3(256), 0, stream,
                     e0, e1, e2, zbf);
  hipLaunchKernelGGL(gemm_loss_kernel, dim3(64, 64, 3), dim3(256), 0, stream,
                     zbf, ids, pPart, nPart);
  hipLaunchKernelGGL(finalize_kernel, dim3(1), dim3(256), 0, stream,
                     hist, pPart, nPart, out);
}